// Round 5
// baseline (415.723 us; speedup 1.0000x reference)
//
#include <hip/hip_runtime.h>
#include <math.h>

// Cone-beam forward projection (TIGRE Ax analogue).
// Volume: [B=2, NZ=96, NY=96, NX=96] f32, ZYX layout (x fastest).
// Output: [B=2, A=48, NV=96, NU=96] f32.
//
// R5: TWO LANES PER RAY (ray = lane>>1, par = lane&1). Each lane gathers the
// 4 (z,y) taps at x0+par, so the x-pair that shares a cacheline is coalesced
// WITHIN one instruction (TCP merges same-line lanes); 8 gathers/sample -> 4,
// each spanning half the u-spread. Even lane pulls partner's x1 values via
// __shfl_xor(.,1) and accumulates the bit-identical lerp chain; odd lane's
// result is unused. Output written by even lanes only.
//
// CORRECTNESS-CRITICAL: reference integrand is DISCONTINUOUS at cube faces.
// Position path replicates the reference's f32 op sequence exactly:
// contract(off), per-sample src + d*t, IEEE sqrt+div, f64-rounded trig.

#define NZg 96
#define NYg 96
#define NXg 96
#define NVg 96
#define NUg 96
#define NAg 48
#define NSg 96
#define NBg 2

__global__ __launch_bounds__(256) void coneproj_kernel(
    const float* __restrict__ vol, float* __restrict__ out) {
#pragma clang fp contract(off)
    const int tid  = blockIdx.x * blockDim.x + threadIdx.x;
    const int par  = tid & 1;          // x-parity handled by this lane
    const int ridx = tid >> 1;         // ray index: ((b*NA+a)*NV+v)*NU+u
    const int u   = ridx % NUg;
    int tmp       = ridx / NUg;
    const int v   = tmp % NVg;
    tmp          /= NVg;
    const int a   = tmp % NAg;
    const int b   = tmp / NAg;

    // theta = a * (f32(2*pi) / 48)   [jax linspace f32 semantics]
    const float dtheta = 6.2831855f / 48.0f;
    const float theta  = (float)a * dtheta;
    const float c = (float)cos((double)theta);
    const float s = (float)sin((double)theta);

    // source / detector pixel (x,y,z), ref op order, f32, no contraction
    const float srcx = 500.0f * c;
    const float srcy = 500.0f * s;
    const float uu = ((float)u - 47.5f) * 2.0f;
    const float vv = ((float)v - 47.5f) * 2.0f;
    const float pixx = (-500.0f * c) + uu * (-s);
    const float pixy = (-500.0f * s) + uu * c;
    const float pixz = vv;

    const float dx0 = pixx - srcx;
    const float dy0 = pixy - srcy;
    const float dz0 = pixz;
    const float nrm = sqrtf((dx0 * dx0 + dy0 * dy0) + dz0 * dz0);
    const float dx = dx0 / nrm;
    const float dy = dy0 / nrm;
    const float dz = dz0 / nrm;

    const float stepf = (float)1.7320508075688773;   // f32(2R/96)
    const float t0f   = (float)416.8615612366939;    // f32(DSO-R)

    // conservative AABB clip of sample range (skip-only; in-loop test is
    // authoritative)
    const float LO = -47.51f, HI = 47.51f;
    float tlo = -1e30f, thi = 1e30f;
    {
        const float o3[3] = {srcx, srcy, 0.0f};
        const float d3[3] = {dx, dy, dz};
        bool empty = false;
        #pragma unroll
        for (int ax = 0; ax < 3; ++ax) {
            const float oo = o3[ax], dd = d3[ax];
            if (fabsf(dd) > 1e-8f) {
                const float inv = 1.0f / dd;
                const float ta = (LO - oo) * inv;
                const float tb = (HI - oo) * inv;
                tlo = fmaxf(tlo, fminf(ta, tb));
                thi = fminf(thi, fmaxf(ta, tb));
            } else if (oo < LO || oo > HI) {
                empty = true;
            }
        }
        if (empty) { tlo = 1.0f; thi = 0.0f; }
    }
    int k0, k1;
    if (thi >= tlo) {
        k0 = (int)floorf((tlo - t0f) / stepf) - 2;
        k1 = (int)ceilf((thi - t0f) / stepf) + 2;
        k0 = max(k0, 0);
        k1 = min(k1, NSg - 1);
    } else {
        k0 = 1; k1 = 0;  // empty
    }

    const float* __restrict__ volb = vol + (size_t)b * (NZg * NYg * NXg);

    float acc = 0.0f;
    for (int k = k0; k <= k1; ++k) {
        const float tk = t0f + ((float)k + 0.5f) * stepf;
        const float ix = (srcx + dx * tk) + 47.5f;
        const float iy = (srcy + dy * tk) + 47.5f;
        const float iz = (dz * tk) + 47.5f;
        if (ix >= 0.0f && ix <= 95.0f &&
            iy >= 0.0f && iy <= 95.0f &&
            iz >= 0.0f && iz <= 95.0f) {
            const int x0 = min((int)ix, NXg - 2);
            const int y0 = min((int)iy, NYg - 2);
            const int z0 = min((int)iz, NZg - 2);
            const float fx = ix - (float)x0;
            const float fy = iy - (float)y0;
            const float fz = iz - (float)z0;
            // this lane loads the 4 (z,y) taps at x0+par; partner has x0+1-par
            const float* pp = volb + ((z0 * NYg + y0) * NXg + x0 + par);
            const float a00 = pp[0];                  // (z0,y0)
            const float a01 = pp[NXg];                // (z0,y1)
            const float a10 = pp[NYg * NXg];          // (z1,y0)
            const float a11 = pp[NYg * NXg + NXg];    // (z1,y1)
            // partner's values (for even lanes these are the x0+1 column;
            // odd lanes compute an unused value)
            const float b00 = __shfl_xor(a00, 1, 64);
            const float b01 = __shfl_xor(a01, 1, 64);
            const float b10 = __shfl_xor(a10, 1, 64);
            const float b11 = __shfl_xor(a11, 1, 64);
            const float c00 = a00 + fx * (b00 - a00);
            const float c01 = a01 + fx * (b01 - a01);
            const float c10 = a10 + fx * (b10 - a10);
            const float c11 = a11 + fx * (b11 - a11);
            const float c0  = c00 + fy * (c01 - c00);
            const float c1  = c10 + fy * (c11 - c10);
            acc += c0 + fz * (c1 - c0);
        }
    }
    if (par == 0) out[ridx] = acc * stepf;
}

extern "C" void kernel_launch(void* const* d_in, const int* in_sizes, int n_in,
                              void* d_out, int out_size, void* d_ws, size_t ws_size,
                              hipStream_t stream) {
    const float* vol = (const float*)d_in[0];
    float* out = (float*)d_out;
    const int total_threads = 2 * NBg * NAg * NVg * NUg;  // 2 lanes per ray
    coneproj_kernel<<<total_threads / 256, 256, 0, stream>>>(vol, out);
}

// Round 6
// 361.709 us; speedup vs baseline: 1.1493x; 1.1493x over previous
//
#include <hip/hip_runtime.h>
#include <math.h>

// Cone-beam forward projection (TIGRE Ax analogue).
// Volume: [B=2, NZ=96, NY=96, NX=96] f32, ZYX layout (x fastest).
// Output: [B=2, A=48, NV=96, NU=96] f32.
//
// R6: PRE-PACKED float4 VOLUME. Staging kernel writes
//   P[b][z][y][x] = (v[z][y][x], v[z][y][x+1], v[z][y+1][x], v[z][y+1][x+1])
// into d_ws; the ray loop then needs only TWO global_load_dwordx4 per sample
// (z0- and z1-plane quads) instead of 8 scalar gathers. Evidence (R3 neutral,
// R5 regression): cost tracks vmem INSTRUCTION count through the per-CU TA,
// not cacheline touches. Tap values and lerp order are bit-identical to R2.
//
// CORRECTNESS-CRITICAL: reference integrand is DISCONTINUOUS at cube faces.
// Position path replicates the reference's f32 op sequence exactly:
// contract(off), per-sample src + d*t, IEEE sqrt+div, f64-rounded trig.

#define NZg 96
#define NYg 96
#define NXg 96
#define NVg 96
#define NUg 96
#define NAg 48
#define NSg 96
#define NBg 2

// ---------------- staging: pack (y,x)-quads into float4 -------------------
__global__ __launch_bounds__(256) void pack_kernel(
    const float* __restrict__ vol, float4* __restrict__ packed) {
    const int i = blockIdx.x * blockDim.x + threadIdx.x;  // [b][z][y][x]
    const int x = i % NXg;
    int t = i / NXg;
    const int y = t % NYg;
    t /= NYg;
    const int z = t % NZg;
    const int b = t / NZg;
    const float* vb = vol + ((size_t)(b * NZg + z)) * (NYg * NXg);
    const int x1 = min(x + 1, NXg - 1);
    const int y1 = min(y + 1, NYg - 1);
    float4 q;
    q.x = vb[y * NXg + x];
    q.y = vb[y * NXg + x1];
    q.z = vb[y1 * NXg + x];
    q.w = vb[y1 * NXg + x1];
    packed[i] = q;
}

// ---------------- shared geometry helper (inlined) ------------------------
// computes everything up to the per-ray k-range; returns via refs
__device__ __forceinline__ void ray_setup(
    int ridx, float& srcx, float& srcy, float& dx, float& dy, float& dz,
    int& k0, int& k1, int& b) {
#pragma clang fp contract(off)
    const int u   = ridx % NUg;
    int tmp       = ridx / NUg;
    const int v   = tmp % NVg;
    tmp          /= NVg;
    const int a   = tmp % NAg;
    b             = tmp / NAg;

    // theta = a * (f32(2*pi) / 48)   [jax linspace f32 semantics]
    const float dtheta = 6.2831855f / 48.0f;
    const float theta  = (float)a * dtheta;
    const float c = (float)cos((double)theta);
    const float s = (float)sin((double)theta);

    srcx = 500.0f * c;
    srcy = 500.0f * s;
    const float uu = ((float)u - 47.5f) * 2.0f;
    const float vv = ((float)v - 47.5f) * 2.0f;
    const float pixx = (-500.0f * c) + uu * (-s);
    const float pixy = (-500.0f * s) + uu * c;
    const float pixz = vv;

    const float dx0 = pixx - srcx;
    const float dy0 = pixy - srcy;
    const float dz0 = pixz;
    const float nrm = sqrtf((dx0 * dx0 + dy0 * dy0) + dz0 * dz0);
    dx = dx0 / nrm;
    dy = dy0 / nrm;
    dz = dz0 / nrm;

    const float stepf = (float)1.7320508075688773;   // f32(2R/96)
    const float t0f   = (float)416.8615612366939;    // f32(DSO-R)

    // conservative AABB clip (skip-only; in-loop test is authoritative)
    const float LO = -47.51f, HI = 47.51f;
    float tlo = -1e30f, thi = 1e30f;
    {
        const float o3[3] = {srcx, srcy, 0.0f};
        const float d3[3] = {dx, dy, dz};
        bool empty = false;
        #pragma unroll
        for (int ax = 0; ax < 3; ++ax) {
            const float oo = o3[ax], dd = d3[ax];
            if (fabsf(dd) > 1e-8f) {
                const float inv = 1.0f / dd;
                const float ta = (LO - oo) * inv;
                const float tb = (HI - oo) * inv;
                tlo = fmaxf(tlo, fminf(ta, tb));
                thi = fminf(thi, fmaxf(ta, tb));
            } else if (oo < LO || oo > HI) {
                empty = true;
            }
        }
        if (empty) { tlo = 1.0f; thi = 0.0f; }
    }
    if (thi >= tlo) {
        k0 = (int)floorf((tlo - t0f) / stepf) - 2;
        k1 = (int)ceilf((thi - t0f) / stepf) + 2;
        k0 = max(k0, 0);
        k1 = min(k1, NSg - 1);
    } else {
        k0 = 1; k1 = 0;
    }
}

// ---------------- main: packed-volume projector ---------------------------
__global__ __launch_bounds__(256) void coneproj_packed(
    const float4* __restrict__ packed, float* __restrict__ out) {
#pragma clang fp contract(off)
    const int ridx = blockIdx.x * blockDim.x + threadIdx.x;
    float srcx, srcy, dx, dy, dz;
    int k0, k1, b;
    ray_setup(ridx, srcx, srcy, dx, dy, dz, k0, k1, b);

    const float stepf = (float)1.7320508075688773;
    const float t0f   = (float)416.8615612366939;

    const float4* __restrict__ pb = packed + (size_t)b * (NZg * NYg * NXg);

    float acc = 0.0f;
    for (int k = k0; k <= k1; ++k) {
        const float tk = t0f + ((float)k + 0.5f) * stepf;
        const float ix = (srcx + dx * tk) + 47.5f;
        const float iy = (srcy + dy * tk) + 47.5f;
        const float iz = (dz * tk) + 47.5f;
        if (ix >= 0.0f && ix <= 95.0f &&
            iy >= 0.0f && iy <= 95.0f &&
            iz >= 0.0f && iz <= 95.0f) {
            const int x0 = min((int)ix, NXg - 2);
            const int y0 = min((int)iy, NYg - 2);
            const int z0 = min((int)iz, NZg - 2);
            const float fx = ix - (float)x0;
            const float fy = iy - (float)y0;
            const float fz = iz - (float)z0;
            const int off0 = (z0 * NYg + y0) * NXg + x0;
            const float4 p0 = pb[off0];                  // z0 quad
            const float4 p1 = pb[off0 + NYg * NXg];      // z1 quad
            const float c00 = p0.x + fx * (p0.y - p0.x);
            const float c01 = p0.z + fx * (p0.w - p0.z);
            const float c10 = p1.x + fx * (p1.y - p1.x);
            const float c11 = p1.z + fx * (p1.w - p1.z);
            const float c0  = c00 + fy * (c01 - c00);
            const float c1  = c10 + fy * (c11 - c10);
            acc += c0 + fz * (c1 - c0);
        }
    }
    out[ridx] = acc * stepf;
}

// ---------------- fallback: direct 8-gather projector (R2) ----------------
__global__ __launch_bounds__(256) void coneproj_direct(
    const float* __restrict__ vol, float* __restrict__ out) {
#pragma clang fp contract(off)
    const int ridx = blockIdx.x * blockDim.x + threadIdx.x;
    float srcx, srcy, dx, dy, dz;
    int k0, k1, b;
    ray_setup(ridx, srcx, srcy, dx, dy, dz, k0, k1, b);

    const float stepf = (float)1.7320508075688773;
    const float t0f   = (float)416.8615612366939;

    const float* __restrict__ volb = vol + (size_t)b * (NZg * NYg * NXg);

    float acc = 0.0f;
    for (int k = k0; k <= k1; ++k) {
        const float tk = t0f + ((float)k + 0.5f) * stepf;
        const float ix = (srcx + dx * tk) + 47.5f;
        const float iy = (srcy + dy * tk) + 47.5f;
        const float iz = (dz * tk) + 47.5f;
        if (ix >= 0.0f && ix <= 95.0f &&
            iy >= 0.0f && iy <= 95.0f &&
            iz >= 0.0f && iz <= 95.0f) {
            const int x0 = min((int)ix, NXg - 2);
            const int y0 = min((int)iy, NYg - 2);
            const int z0 = min((int)iz, NZg - 2);
            const float fx = ix - (float)x0;
            const float fy = iy - (float)y0;
            const float fz = iz - (float)z0;
            const float* p = volb + ((z0 * NYg + y0) * NXg + x0);
            const float v000 = p[0];
            const float v001 = p[1];
            const float v010 = p[NXg];
            const float v011 = p[NXg + 1];
            const float v100 = p[NYg * NXg];
            const float v101 = p[NYg * NXg + 1];
            const float v110 = p[NYg * NXg + NXg];
            const float v111 = p[NYg * NXg + NXg + 1];
            const float c00 = v000 + fx * (v001 - v000);
            const float c01 = v010 + fx * (v011 - v010);
            const float c10 = v100 + fx * (v101 - v100);
            const float c11 = v110 + fx * (v111 - v110);
            const float c0  = c00 + fy * (c01 - c00);
            const float c1  = c10 + fy * (c11 - c10);
            acc += c0 + fz * (c1 - c0);
        }
    }
    out[ridx] = acc * stepf;
}

extern "C" void kernel_launch(void* const* d_in, const int* in_sizes, int n_in,
                              void* d_out, int out_size, void* d_ws, size_t ws_size,
                              hipStream_t stream) {
    const float* vol = (const float*)d_in[0];
    float* out = (float*)d_out;
    const int nvox  = NBg * NZg * NYg * NXg;          // 1,769,472
    const int nrays = NBg * NAg * NVg * NUg;          // 884,736 == out_size
    const size_t needed = (size_t)nvox * sizeof(float4);  // ~28.3 MB
    if (ws_size >= needed) {
        float4* packed = (float4*)d_ws;
        pack_kernel<<<nvox / 256, 256, 0, stream>>>(vol, packed);
        coneproj_packed<<<nrays / 256, 256, 0, stream>>>(packed, out);
    } else {
        coneproj_direct<<<nrays / 256, 256, 0, stream>>>(vol, out);
    }
}

// Round 7
// 214.783 us; speedup vs baseline: 1.9355x; 1.6841x over previous
//
#include <hip/hip_runtime.h>
#include <math.h>

// Cone-beam forward projection (TIGRE Ax analogue).
// Volume: [B=2, NZ=96, NY=96, NX=96] f32, ZYX layout (x fastest).
// Output: [B=2, A=48, NV=96, NU=96] f32.
//
// R7: BATCH-INTERLEAVED PAIR VOLUME. Q[z][y][x] = (v_b0, v_b1) as aligned
// float2 (7.1 MB — same L2-resident footprint class as the raw volume, unlike
// R6's 28 MB which went L2-miss-bound at 506 MB FETCH). One thread serves
// BOTH batches (geometry is b-independent): 8 aligned dwordx2 gathers deliver
// the 8 trilinear corners for two ray-samples -> line-passes per sample drop
// ~2-4x and geometry VALU is amortized 2x. Per-batch lerp chain and k-order
// are op-for-op identical to R2 -> bit-identical output.
//
// CORRECTNESS-CRITICAL: reference integrand is DISCONTINUOUS at cube faces.
// Position path replicates the reference's f32 op sequence exactly:
// contract(off), per-sample src + d*t, IEEE sqrt+div, f64-rounded trig.

#define NZg 96
#define NYg 96
#define NXg 96
#define NVg 96
#define NUg 96
#define NAg 48
#define NSg 96
#define NBg 2
#define NVOX (NZg * NYg * NXg)          // 884736 voxels per batch
#define NRAY1 (NAg * NVg * NUg)         // 442368 rays per batch

// ---------------- staging: interleave the two batches ---------------------
__global__ __launch_bounds__(256) void pack_b2(
    const float* __restrict__ vol, float2* __restrict__ q) {
    const int i = blockIdx.x * blockDim.x + threadIdx.x;  // [z][y][x]
    float2 p;
    p.x = vol[i];
    p.y = vol[i + NVOX];
    q[i] = p;
}

// ---------------- shared geometry (b-independent) -------------------------
__device__ __forceinline__ void ray_setup(
    int ridx, float& srcx, float& srcy, float& dx, float& dy, float& dz,
    int& k0, int& k1) {
#pragma clang fp contract(off)
    const int u   = ridx % NUg;
    int tmp       = ridx / NUg;
    const int v   = tmp % NVg;
    const int a   = tmp / NVg;          // < 48

    // theta = a * (f32(2*pi) / 48)   [jax linspace f32 semantics]
    const float dtheta = 6.2831855f / 48.0f;
    const float theta  = (float)a * dtheta;
    const float c = (float)cos((double)theta);
    const float s = (float)sin((double)theta);

    srcx = 500.0f * c;
    srcy = 500.0f * s;
    const float uu = ((float)u - 47.5f) * 2.0f;
    const float vv = ((float)v - 47.5f) * 2.0f;
    const float pixx = (-500.0f * c) + uu * (-s);
    const float pixy = (-500.0f * s) + uu * c;
    const float pixz = vv;

    const float dx0 = pixx - srcx;
    const float dy0 = pixy - srcy;
    const float dz0 = pixz;
    const float nrm = sqrtf((dx0 * dx0 + dy0 * dy0) + dz0 * dz0);
    dx = dx0 / nrm;
    dy = dy0 / nrm;
    dz = dz0 / nrm;

    const float stepf = (float)1.7320508075688773;   // f32(2R/96)
    const float t0f   = (float)416.8615612366939;    // f32(DSO-R)

    // conservative AABB clip (skip-only; in-loop test is authoritative)
    const float LO = -47.51f, HI = 47.51f;
    float tlo = -1e30f, thi = 1e30f;
    {
        const float o3[3] = {srcx, srcy, 0.0f};
        const float d3[3] = {dx, dy, dz};
        bool empty = false;
        #pragma unroll
        for (int ax = 0; ax < 3; ++ax) {
            const float oo = o3[ax], dd = d3[ax];
            if (fabsf(dd) > 1e-8f) {
                const float inv = 1.0f / dd;
                const float ta = (LO - oo) * inv;
                const float tb = (HI - oo) * inv;
                tlo = fmaxf(tlo, fminf(ta, tb));
                thi = fminf(thi, fmaxf(ta, tb));
            } else if (oo < LO || oo > HI) {
                empty = true;
            }
        }
        if (empty) { tlo = 1.0f; thi = 0.0f; }
    }
    if (thi >= tlo) {
        k0 = (int)floorf((tlo - t0f) / stepf) - 2;
        k1 = (int)ceilf((thi - t0f) / stepf) + 2;
        k0 = max(k0, 0);
        k1 = min(k1, NSg - 1);
    } else {
        k0 = 1; k1 = 0;
    }
}

// ---------------- main: both batches per thread ---------------------------
__global__ __launch_bounds__(256) void coneproj_b2(
    const float2* __restrict__ q, float* __restrict__ out) {
#pragma clang fp contract(off)
    const int ridx = blockIdx.x * blockDim.x + threadIdx.x;  // (a*96+v)*96+u
    float srcx, srcy, dx, dy, dz;
    int k0, k1;
    ray_setup(ridx, srcx, srcy, dx, dy, dz, k0, k1);

    const float stepf = (float)1.7320508075688773;
    const float t0f   = (float)416.8615612366939;

    float acc0 = 0.0f, acc1 = 0.0f;
    for (int k = k0; k <= k1; ++k) {
        const float tk = t0f + ((float)k + 0.5f) * stepf;
        const float ix = (srcx + dx * tk) + 47.5f;
        const float iy = (srcy + dy * tk) + 47.5f;
        const float iz = (dz * tk) + 47.5f;
        if (ix >= 0.0f && ix <= 95.0f &&
            iy >= 0.0f && iy <= 95.0f &&
            iz >= 0.0f && iz <= 95.0f) {
            const int x0 = min((int)ix, NXg - 2);
            const int y0 = min((int)iy, NYg - 2);
            const int z0 = min((int)iz, NZg - 2);
            const float fx = ix - (float)x0;
            const float fy = iy - (float)y0;
            const float fz = iz - (float)z0;
            const int off0 = (z0 * NYg + y0) * NXg + x0;
            // 8 aligned dwordx2 gathers; each carries BOTH batches' value
            const float2 q000 = q[off0];
            const float2 q001 = q[off0 + 1];
            const float2 q010 = q[off0 + NXg];
            const float2 q011 = q[off0 + NXg + 1];
            const float2 q100 = q[off0 + NYg * NXg];
            const float2 q101 = q[off0 + NYg * NXg + 1];
            const float2 q110 = q[off0 + NYg * NXg + NXg];
            const float2 q111 = q[off0 + NYg * NXg + NXg + 1];
            // batch 0 (op-order identical to R2)
            {
                const float c00 = q000.x + fx * (q001.x - q000.x);
                const float c01 = q010.x + fx * (q011.x - q010.x);
                const float c10 = q100.x + fx * (q101.x - q100.x);
                const float c11 = q110.x + fx * (q111.x - q110.x);
                const float c0  = c00 + fy * (c01 - c00);
                const float c1  = c10 + fy * (c11 - c10);
                acc0 += c0 + fz * (c1 - c0);
            }
            // batch 1
            {
                const float c00 = q000.y + fx * (q001.y - q000.y);
                const float c01 = q010.y + fx * (q011.y - q010.y);
                const float c10 = q100.y + fx * (q101.y - q100.y);
                const float c11 = q110.y + fx * (q111.y - q110.y);
                const float c0  = c00 + fy * (c01 - c00);
                const float c1  = c10 + fy * (c11 - c10);
                acc1 += c0 + fz * (c1 - c0);
            }
        }
    }
    out[ridx]         = acc0 * stepf;
    out[ridx + NRAY1] = acc1 * stepf;
}

// ---------------- fallback: direct 8-gather projector (R2) ----------------
__global__ __launch_bounds__(256) void coneproj_direct(
    const float* __restrict__ vol, float* __restrict__ out) {
#pragma clang fp contract(off)
    const int gidx = blockIdx.x * blockDim.x + threadIdx.x;  // includes b
    const int ridx = gidx % NRAY1;
    const int b    = gidx / NRAY1;
    float srcx, srcy, dx, dy, dz;
    int k0, k1;
    ray_setup(ridx, srcx, srcy, dx, dy, dz, k0, k1);

    const float stepf = (float)1.7320508075688773;
    const float t0f   = (float)416.8615612366939;

    const float* __restrict__ volb = vol + (size_t)b * NVOX;

    float acc = 0.0f;
    for (int k = k0; k <= k1; ++k) {
        const float tk = t0f + ((float)k + 0.5f) * stepf;
        const float ix = (srcx + dx * tk) + 47.5f;
        const float iy = (srcy + dy * tk) + 47.5f;
        const float iz = (dz * tk) + 47.5f;
        if (ix >= 0.0f && ix <= 95.0f &&
            iy >= 0.0f && iy <= 95.0f &&
            iz >= 0.0f && iz <= 95.0f) {
            const int x0 = min((int)ix, NXg - 2);
            const int y0 = min((int)iy, NYg - 2);
            const int z0 = min((int)iz, NZg - 2);
            const float fx = ix - (float)x0;
            const float fy = iy - (float)y0;
            const float fz = iz - (float)z0;
            const float* p = volb + ((z0 * NYg + y0) * NXg + x0);
            const float v000 = p[0];
            const float v001 = p[1];
            const float v010 = p[NXg];
            const float v011 = p[NXg + 1];
            const float v100 = p[NYg * NXg];
            const float v101 = p[NYg * NXg + 1];
            const float v110 = p[NYg * NXg + NXg];
            const float v111 = p[NYg * NXg + NXg + 1];
            const float c00 = v000 + fx * (v001 - v000);
            const float c01 = v010 + fx * (v011 - v010);
            const float c10 = v100 + fx * (v101 - v100);
            const float c11 = v110 + fx * (v111 - v110);
            const float c0  = c00 + fy * (c01 - c00);
            const float c1  = c10 + fy * (c11 - c10);
            acc += c0 + fz * (c1 - c0);
        }
    }
    out[gidx] = acc * stepf;
}

extern "C" void kernel_launch(void* const* d_in, const int* in_sizes, int n_in,
                              void* d_out, int out_size, void* d_ws, size_t ws_size,
                              hipStream_t stream) {
    const float* vol = (const float*)d_in[0];
    float* out = (float*)d_out;
    const size_t needed = (size_t)NVOX * sizeof(float2);  // ~7.1 MB
    if (ws_size >= needed) {
        float2* q = (float2*)d_ws;
        pack_b2<<<NVOX / 256, 256, 0, stream>>>(vol, q);
        coneproj_b2<<<NRAY1 / 256, 256, 0, stream>>>(q, out);
    } else {
        coneproj_direct<<<(NBg * NRAY1) / 256, 256, 0, stream>>>(vol, out);
    }
}